// Round 1
// baseline (761.556 us; speedup 1.0000x reference)
//
#include <hip/hip_runtime.h>
#include <math.h>

#define N_NODES 50000
#define N_EDGES 800000
#define D 64

// ---------------------------------------------------------------------------
// degree / normalization
// ---------------------------------------------------------------------------
__global__ void k_init_deg(float* __restrict__ deg) {
    int i = blockIdx.x * blockDim.x + threadIdx.x;
    if (i < N_NODES) deg[i] = 1.0f;   // self-loop contributes 1
}

__global__ void k_count_deg(const int* __restrict__ dst, float* __restrict__ deg) {
    int e = blockIdx.x * blockDim.x + threadIdx.x;
    if (e < N_EDGES) atomicAdd(&deg[dst[e]], 1.0f);
}

__global__ void k_dinv(float* __restrict__ deg) {
    int i = blockIdx.x * blockDim.x + threadIdx.x;
    if (i < N_NODES) deg[i] = rsqrtf(deg[i]);
}

// ---------------------------------------------------------------------------
// GEMM: out[N,64] = h[N,64(stride)] @ W[64,64]
// block = 256 threads, 16 rows per block. W staged in LDS (16 KB), h tile in
// LDS (4 KB). Ws[k][col] read: 64 consecutive cols -> 2 lanes/bank (free).
// hs[r][k]: same-address broadcast (free).
// ---------------------------------------------------------------------------
__global__ void k_gemm64(const float* __restrict__ h, int hstride,
                         const float* __restrict__ W, float* __restrict__ out) {
    __shared__ float Ws[64][64];
    __shared__ float hs[16][64];
    int tid = threadIdx.x;
    for (int i = tid; i < 64 * 64; i += 256) Ws[i >> 6][i & 63] = W[i];
    int row0 = blockIdx.x * 16;
    for (int i = tid; i < 16 * 64; i += 256) {
        int r = row0 + (i >> 6);
        hs[i >> 6][i & 63] = (r < N_NODES) ? h[(size_t)r * hstride + (i & 63)] : 0.0f;
    }
    __syncthreads();
    int col = tid & 63;
    int rsub = tid >> 6;           // 0..3
    #pragma unroll
    for (int p = 0; p < 4; ++p) {
        int r = p * 4 + rsub;
        float acc = 0.0f;
        #pragma unroll
        for (int k = 0; k < 64; ++k) acc += hs[r][k] * Ws[k][col];
        int grow = row0 + r;
        if (grow < N_NODES) out[(size_t)grow * D + col] = acc;
    }
}

// ---------------------------------------------------------------------------
// agg = b + hW * dinv^2   (self-loop message + bias), run before edge scatter
// ---------------------------------------------------------------------------
__global__ void k_init_agg(const float* __restrict__ hW, const float* __restrict__ dinv,
                           const float* __restrict__ b, float* __restrict__ agg) {
    int idx = blockIdx.x * blockDim.x + threadIdx.x;
    if (idx < N_NODES * D) {
        int i = idx >> 6, f = idx & 63;
        float di = dinv[i];
        agg[idx] = b[f] + hW[idx] * di * di;
    }
}

// ---------------------------------------------------------------------------
// edge scatter: agg[dst] += hW[src] * dinv[src]*dinv[dst]
// 64 threads per edge (one per feature), 4 edges per block
// ---------------------------------------------------------------------------
__global__ void k_scatter(const int* __restrict__ src, const int* __restrict__ dst,
                          const float* __restrict__ dinv, const float* __restrict__ hW,
                          float* __restrict__ agg) {
    long long idx = (long long)blockIdx.x * blockDim.x + threadIdx.x;
    int e = (int)(idx >> 6);
    if (e >= N_EDGES) return;
    int f = (int)(idx & 63);
    int s = src[e];
    int d = dst[e];
    float w = dinv[s] * dinv[d];
    atomicAdd(&agg[(size_t)d * D + f], hW[(size_t)s * D + f] * w);
}

// ---------------------------------------------------------------------------
// elu + strided store into concat output [N, 192]
// ---------------------------------------------------------------------------
__global__ void k_elu_store(const float* __restrict__ agg, float* __restrict__ out,
                            int col_off) {
    int idx = blockIdx.x * blockDim.x + threadIdx.x;
    if (idx < N_NODES * D) {
        int i = idx >> 6, f = idx & 63;
        float v = agg[idx];
        v = (v > 0.0f) ? v : expm1f(v);
        out[(size_t)i * (3 * D) + col_off + f] = v;
    }
}

extern "C" void kernel_launch(void* const* d_in, const int* in_sizes, int n_in,
                              void* d_out, int out_size, void* d_ws, size_t ws_size,
                              hipStream_t stream) {
    const float* x   = (const float*)d_in[0];
    const int*   ei  = (const int*)d_in[1];
    const int*   src = ei;
    const int*   dst = ei + N_EDGES;
    const float* W[3] = {(const float*)d_in[2], (const float*)d_in[4], (const float*)d_in[6]};
    const float* b[3] = {(const float*)d_in[3], (const float*)d_in[5], (const float*)d_in[7]};
    float* out = (float*)d_out;

    float* dinv = (float*)d_ws;                 // N floats (holds deg then dinv)
    float* hW   = dinv + N_NODES;               // N*D floats
    float* agg  = hW + (size_t)N_NODES * D;     // N*D floats

    // normalization
    k_init_deg<<<(N_NODES + 255) / 256, 256, 0, stream>>>(dinv);
    k_count_deg<<<(N_EDGES + 255) / 256, 256, 0, stream>>>(dst, dinv);
    k_dinv<<<(N_NODES + 255) / 256, 256, 0, stream>>>(dinv);

    const float* hin = x;
    int hstride = D;
    const int elem = N_NODES * D;
    for (int l = 0; l < 3; ++l) {
        k_gemm64<<<(N_NODES + 15) / 16, 256, 0, stream>>>(hin, hstride, W[l], hW);
        k_init_agg<<<(elem + 255) / 256, 256, 0, stream>>>(hW, dinv, b[l], agg);
        long long sthreads = (long long)N_EDGES * D;
        k_scatter<<<(int)((sthreads + 255) / 256), 256, 0, stream>>>(src, dst, dinv, hW, agg);
        k_elu_store<<<(elem + 255) / 256, 256, 0, stream>>>(agg, out, l * D);
        hin = out + l * D;      // read this layer's elu output back, strided
        hstride = 3 * D;
    }
}

// Round 2
// 387.112 us; speedup vs baseline: 1.9673x; 1.9673x over previous
//
#include <hip/hip_runtime.h>
#include <math.h>

#define N_NODES 50000
#define N_EDGES 800000
#define D 64
#define SCAN_B 256
#define NBLK1 ((N_NODES + SCAN_B - 1) / SCAN_B)   // 196

// ---------------------------------------------------------------------------
// CSR build: zero counters
// ---------------------------------------------------------------------------
__global__ void k_zero(int* __restrict__ cnt, int* __restrict__ cursor) {
    int i = blockIdx.x * blockDim.x + threadIdx.x;
    if (i < N_NODES) { cnt[i] = 0; cursor[i] = 0; }
}

__global__ void k_count(const int* __restrict__ dst, int* __restrict__ cnt) {
    int e = blockIdx.x * blockDim.x + threadIdx.x;
    if (e < N_EDGES) atomicAdd(&cnt[dst[e]], 1);
}

// per-block exclusive scan of cnt -> row_start (partial), block totals -> bsum
__global__ void k_scan1(const int* __restrict__ cnt, int* __restrict__ row_start,
                        int* __restrict__ bsum) {
    __shared__ int s[SCAN_B];
    int t = threadIdx.x;
    int i = blockIdx.x * SCAN_B + t;
    int v = (i < N_NODES) ? cnt[i] : 0;
    s[t] = v;
    __syncthreads();
    #pragma unroll
    for (int off = 1; off < SCAN_B; off <<= 1) {
        int u = (t >= off) ? s[t - off] : 0;
        __syncthreads();
        s[t] += u;
        __syncthreads();
    }
    if (i < N_NODES) row_start[i] = s[t] - v;      // exclusive within block
    if (t == SCAN_B - 1) bsum[blockIdx.x] = s[t];  // block total
}

// single-block exclusive scan of bsum
__global__ void k_scan2(int* __restrict__ bsum) {
    __shared__ int s[SCAN_B];
    int t = threadIdx.x;
    int v = (t < NBLK1) ? bsum[t] : 0;
    s[t] = v;
    __syncthreads();
    #pragma unroll
    for (int off = 1; off < SCAN_B; off <<= 1) {
        int u = (t >= off) ? s[t - off] : 0;
        __syncthreads();
        s[t] += u;
        __syncthreads();
    }
    if (t < NBLK1) bsum[t] = s[t] - v;             // exclusive
}

// add block offsets; compute dinv = rsqrt(deg) with deg = cnt + 1 (self loop)
__global__ void k_scan3(int* __restrict__ row_start, const int* __restrict__ bsum,
                        const int* __restrict__ cnt, float* __restrict__ dinv) {
    int i = blockIdx.x * blockDim.x + threadIdx.x;
    if (i < N_NODES) {
        row_start[i] += bsum[i / SCAN_B];
        dinv[i] = rsqrtf((float)cnt[i] + 1.0f);
    }
}

// fill CSR: csr_src[pos] = src, csr_w[pos] = dinv[src]*dinv[dst]
__global__ void k_fill(const int* __restrict__ src, const int* __restrict__ dst,
                       const int* __restrict__ row_start, int* __restrict__ cursor,
                       const float* __restrict__ dinv,
                       int* __restrict__ csr_src, float* __restrict__ csr_w) {
    int e = blockIdx.x * blockDim.x + threadIdx.x;
    if (e >= N_EDGES) return;
    int s = src[e], d = dst[e];
    int pos = row_start[d] + atomicAdd(&cursor[d], 1);
    csr_src[pos] = s;
    csr_w[pos] = dinv[s] * dinv[d];
}

// ---------------------------------------------------------------------------
// GEMM: hW[N,64] = h[N,stride] @ W[64,64]
// 256 threads / 64 rows per block. W^T column in 64 VGPRs (coalesced global
// load, L2-resident); h tile in LDS, read as broadcast float4 (ds_read_b128).
// ---------------------------------------------------------------------------
__global__ __launch_bounds__(256) void k_gemm64(const float* __restrict__ h, int hstride,
                                                const float* __restrict__ W,
                                                float* __restrict__ hW) {
    __shared__ float hs[64][64];   // 16 KB
    int tid = threadIdx.x;
    int col = tid & 63;
    int row0 = blockIdx.x * 64;

    float wreg[64];
    #pragma unroll
    for (int k = 0; k < 64; ++k) wreg[k] = W[k * 64 + col];   // coalesced per k

    for (int i = tid; i < 64 * 64; i += 256) {
        int r = i >> 6, c = i & 63;
        int gr = row0 + r;
        hs[r][c] = (gr < N_NODES) ? h[(size_t)gr * hstride + c] : 0.0f;
    }
    __syncthreads();

    int rsub = tid >> 6;   // 0..3
    #pragma unroll
    for (int p = 0; p < 16; ++p) {
        int r = p * 4 + rsub;
        float acc = 0.0f;
        const float4* hp = (const float4*)hs[r];
        #pragma unroll
        for (int kk = 0; kk < 16; ++kk) {
            float4 hv = hp[kk];    // same addr for all lanes -> b128 broadcast
            acc += hv.x * wreg[4 * kk] + hv.y * wreg[4 * kk + 1]
                 + hv.z * wreg[4 * kk + 2] + hv.w * wreg[4 * kk + 3];
        }
        int gr = row0 + r;
        if (gr < N_NODES) hW[((size_t)gr << 6) + col] = acc;
    }
}

// ---------------------------------------------------------------------------
// Fused aggregate: wave per node, lane per feature.
// acc = b + hW[node]*dinv^2 + sum_edges hW[src]*w ; elu ; strided concat store
// ---------------------------------------------------------------------------
__global__ void k_gather_elu(const float* __restrict__ hW,
                             const int* __restrict__ row_start,
                             const int* __restrict__ cnt,
                             const int* __restrict__ csr_src,
                             const float* __restrict__ csr_w,
                             const float* __restrict__ dinv,
                             const float* __restrict__ bias,
                             float* __restrict__ out, int col_off) {
    int gid = blockIdx.x * blockDim.x + threadIdx.x;
    int node = gid >> 6;
    if (node >= N_NODES) return;
    int f = gid & 63;
    float di = dinv[node];
    float acc = bias[f] + hW[((size_t)node << 6) + f] * di * di;
    int beg = row_start[node];
    int n = cnt[node];
    int j = 0;
    for (; j + 2 <= n; j += 2) {
        int s0 = csr_src[beg + j];
        int s1 = csr_src[beg + j + 1];
        float w0 = csr_w[beg + j];
        float w1 = csr_w[beg + j + 1];
        float v0 = hW[((size_t)s0 << 6) + f];
        float v1 = hW[((size_t)s1 << 6) + f];
        acc += v0 * w0 + v1 * w1;
    }
    if (j < n) {
        int s0 = csr_src[beg + j];
        acc += hW[((size_t)s0 << 6) + f] * csr_w[beg + j];
    }
    acc = (acc > 0.0f) ? acc : expm1f(acc);
    out[(size_t)node * (3 * D) + col_off + f] = acc;
}

extern "C" void kernel_launch(void* const* d_in, const int* in_sizes, int n_in,
                              void* d_out, int out_size, void* d_ws, size_t ws_size,
                              hipStream_t stream) {
    const float* x   = (const float*)d_in[0];
    const int*   ei  = (const int*)d_in[1];
    const int*   src = ei;
    const int*   dst = ei + N_EDGES;
    const float* W[3] = {(const float*)d_in[2], (const float*)d_in[4], (const float*)d_in[6]};
    const float* b[3] = {(const float*)d_in[3], (const float*)d_in[5], (const float*)d_in[7]};
    float* out = (float*)d_out;

    // workspace layout
    char* ws = (char*)d_ws;
    float* dinv      = (float*)ws;                          ws += N_NODES * 4;
    int*   cnt       = (int*)ws;                            ws += N_NODES * 4;
    int*   cursor    = (int*)ws;                            ws += N_NODES * 4;
    int*   row_start = (int*)ws;                            ws += N_NODES * 4;
    int*   bsum      = (int*)ws;                            ws += SCAN_B * 4;
    int*   csr_src   = (int*)ws;                            ws += (size_t)N_EDGES * 4;
    float* csr_w     = (float*)ws;                          ws += (size_t)N_EDGES * 4;
    float* hW        = (float*)ws;

    // CSR build (once per call)
    k_zero <<<(N_NODES + 255) / 256, 256, 0, stream>>>(cnt, cursor);
    k_count<<<(N_EDGES + 255) / 256, 256, 0, stream>>>(dst, cnt);
    k_scan1<<<NBLK1, SCAN_B, 0, stream>>>(cnt, row_start, bsum);
    k_scan2<<<1, SCAN_B, 0, stream>>>(bsum);
    k_scan3<<<(N_NODES + 255) / 256, 256, 0, stream>>>(row_start, bsum, cnt, dinv);
    k_fill <<<(N_EDGES + 255) / 256, 256, 0, stream>>>(src, dst, row_start, cursor,
                                                       dinv, csr_src, csr_w);

    const float* hin = x;
    int hstride = D;
    for (int l = 0; l < 3; ++l) {
        k_gemm64<<<(N_NODES + 63) / 64, 256, 0, stream>>>(hin, hstride, W[l], hW);
        long long gthreads = (long long)N_NODES * D;
        k_gather_elu<<<(int)((gthreads + 255) / 256), 256, 0, stream>>>(
            hW, row_start, cnt, csr_src, csr_w, dinv, b[l], out, l * D);
        hin = out + l * D;      // read this layer's elu output back, strided
        hstride = 3 * D;
    }
}

// Round 4
// 323.176 us; speedup vs baseline: 2.3565x; 1.1978x over previous
//
#include <hip/hip_runtime.h>
#include <hip/hip_fp16.h>
#include <math.h>

#define N_NODES 50000
#define N_EDGES 800000
#define D 64
#define SCAN_B 256
#define NBLK1 ((N_NODES + SCAN_B - 1) / SCAN_B)   // 196

// ---------------------------------------------------------------------------
// CSR build
// ---------------------------------------------------------------------------
__global__ void k_zero(int* __restrict__ cnt) {
    int i = blockIdx.x * blockDim.x + threadIdx.x;
    if (i < N_NODES) cnt[i] = 0;
}

__global__ void k_count(const int* __restrict__ dst, int* __restrict__ cnt) {
    int e = blockIdx.x * blockDim.x + threadIdx.x;
    if (e < N_EDGES) atomicAdd(&cnt[dst[e]], 1);
}

// per-block exclusive scan of cnt -> row_start (partial), block totals -> bsum
__global__ void k_scan1(const int* __restrict__ cnt, int* __restrict__ row_start,
                        int* __restrict__ bsum) {
    __shared__ int s[SCAN_B];
    int t = threadIdx.x;
    int i = blockIdx.x * SCAN_B + t;
    int v = (i < N_NODES) ? cnt[i] : 0;
    s[t] = v;
    __syncthreads();
    #pragma unroll
    for (int off = 1; off < SCAN_B; off <<= 1) {
        int u = (t >= off) ? s[t - off] : 0;
        __syncthreads();
        s[t] += u;
        __syncthreads();
    }
    if (i < N_NODES) row_start[i] = s[t] - v;      // exclusive within block
    if (t == SCAN_B - 1) bsum[blockIdx.x] = s[t];  // block total
}

// single-block exclusive scan of bsum
__global__ void k_scan2(int* __restrict__ bsum) {
    __shared__ int s[SCAN_B];
    int t = threadIdx.x;
    int v = (t < NBLK1) ? bsum[t] : 0;
    s[t] = v;
    __syncthreads();
    #pragma unroll
    for (int off = 1; off < SCAN_B; off <<= 1) {
        int u = (t >= off) ? s[t - off] : 0;
        __syncthreads();
        s[t] += u;
        __syncthreads();
    }
    if (t < NBLK1) bsum[t] = s[t] - v;             // exclusive
}

// add block offsets; cursor = row_start; dinv = rsqrt(cnt + 1)
__global__ void k_scan3(int* __restrict__ row_start, const int* __restrict__ bsum,
                        const int* __restrict__ cnt, int* __restrict__ cursor,
                        float* __restrict__ dinv) {
    int i = blockIdx.x * blockDim.x + threadIdx.x;
    if (i < N_NODES) {
        int rs = row_start[i] + bsum[i / SCAN_B];
        row_start[i] = rs;
        cursor[i] = rs;
        dinv[i] = rsqrtf((float)cnt[i] + 1.0f);
    }
}

// fill CSR: csr_ew[pos] = (src, dinv[src]*dinv[dst])
__global__ void k_fill(const int* __restrict__ src, const int* __restrict__ dst,
                       int* __restrict__ cursor, const float* __restrict__ dinv,
                       uint2* __restrict__ csr_ew) {
    int e = blockIdx.x * blockDim.x + threadIdx.x;
    if (e >= N_EDGES) return;
    int s = src[e], d = dst[e];
    int pos = atomicAdd(&cursor[d], 1);
    float w = dinv[s] * dinv[d];
    csr_ew[pos] = make_uint2((unsigned)s, __float_as_uint(w));
}

// ---------------------------------------------------------------------------
// GEMM: hW[N,64](fp16) = h[N,stride](fp32) @ W[64,64]
// 256 threads / 64 rows per block. W column in 64 VGPRs; h tile in LDS read
// as broadcast float4.
// ---------------------------------------------------------------------------
__global__ __launch_bounds__(256) void k_gemm64(const float* __restrict__ h, int hstride,
                                                const float* __restrict__ W,
                                                __half* __restrict__ hWh) {
    __shared__ float hs[64][64];   // 16 KB
    int tid = threadIdx.x;
    int col = tid & 63;
    int row0 = blockIdx.x * 64;

    float wreg[64];
    #pragma unroll
    for (int k = 0; k < 64; ++k) wreg[k] = W[k * 64 + col];   // coalesced per k

    for (int i = tid; i < 64 * 64; i += 256) {
        int r = i >> 6, c = i & 63;
        int gr = row0 + r;
        hs[r][c] = (gr < N_NODES) ? h[(size_t)gr * hstride + c] : 0.0f;
    }
    __syncthreads();

    int rsub = tid >> 6;   // 0..3
    #pragma unroll
    for (int p = 0; p < 16; ++p) {
        int r = p * 4 + rsub;
        float acc = 0.0f;
        const float4* hp = (const float4*)hs[r];
        #pragma unroll
        for (int kk = 0; kk < 16; ++kk) {
            float4 hv = hp[kk];    // same addr for all lanes -> b128 broadcast
            acc += hv.x * wreg[4 * kk] + hv.y * wreg[4 * kk + 1]
                 + hv.z * wreg[4 * kk + 2] + hv.w * wreg[4 * kk + 3];
        }
        int gr = row0 + r;
        if (gr < N_NODES) hWh[((size_t)gr << 6) + col] = __float2half_rn(acc);
    }
}

// ---------------------------------------------------------------------------
// Fused aggregate: half-wave (32 lanes) per node, lane owns a feature PAIR
// (one half2 load). acc = b + hW[node]*dinv^2 + sum_e hW[src]*w ; elu ;
// strided concat store as float2.
// ---------------------------------------------------------------------------
__global__ __launch_bounds__(256) void k_gather_elu(
        const unsigned* __restrict__ hW2,      // [N][32] half2-packed
        const int* __restrict__ row_start,
        const int* __restrict__ cnt,
        const uint2* __restrict__ csr_ew,
        const float* __restrict__ dinv,
        const float* __restrict__ bias,
        float* __restrict__ out, int col_off) {
    int gid = blockIdx.x * blockDim.x + threadIdx.x;
    int node = gid >> 5;
    if (node >= N_NODES) return;
    int fp = gid & 31;
    float di = dinv[node];
    float sw = di * di;
    unsigned sv = hW2[((size_t)node << 5) + fp];
    float2 sf = __half22float2(*(const __half2*)&sv);
    float acc0 = bias[2 * fp]     + sf.x * sw;
    float acc1 = bias[2 * fp + 1] + sf.y * sw;
    int beg = row_start[node];
    int n = cnt[node];
    int j = 0;
    for (; j + 2 <= n; j += 2) {
        uint2 e0 = csr_ew[beg + j];
        uint2 e1 = csr_ew[beg + j + 1];
        float w0 = __uint_as_float(e0.y);
        float w1 = __uint_as_float(e1.y);
        unsigned v0 = hW2[((size_t)e0.x << 5) + fp];
        unsigned v1 = hW2[((size_t)e1.x << 5) + fp];
        float2 f0 = __half22float2(*(const __half2*)&v0);
        float2 f1 = __half22float2(*(const __half2*)&v1);
        acc0 += w0 * f0.x + w1 * f1.x;
        acc1 += w0 * f0.y + w1 * f1.y;
    }
    if (j < n) {
        uint2 e0 = csr_ew[beg + j];
        float w0 = __uint_as_float(e0.y);
        unsigned v0 = hW2[((size_t)e0.x << 5) + fp];
        float2 f0 = __half22float2(*(const __half2*)&v0);
        acc0 += w0 * f0.x;
        acc1 += w0 * f0.y;
    }
    acc0 = (acc0 > 0.0f) ? acc0 : expm1f(acc0);
    acc1 = (acc1 > 0.0f) ? acc1 : expm1f(acc1);
    float2 res = make_float2(acc0, acc1);
    *(float2*)&out[(size_t)node * (3 * D) + col_off + 2 * fp] = res;
}

extern "C" void kernel_launch(void* const* d_in, const int* in_sizes, int n_in,
                              void* d_out, int out_size, void* d_ws, size_t ws_size,
                              hipStream_t stream) {
    const float* x   = (const float*)d_in[0];
    const int*   ei  = (const int*)d_in[1];
    const int*   src = ei;
    const int*   dst = ei + N_EDGES;
    const float* W[3] = {(const float*)d_in[2], (const float*)d_in[4], (const float*)d_in[6]};
    const float* b[3] = {(const float*)d_in[3], (const float*)d_in[5], (const float*)d_in[7]};
    float* out = (float*)d_out;

    // workspace layout (keep 8B alignment for csr_ew)
    char* ws = (char*)d_ws;
    float* dinv      = (float*)ws;                          ws += N_NODES * 4;
    int*   cnt       = (int*)ws;                            ws += N_NODES * 4;
    int*   cursor    = (int*)ws;                            ws += N_NODES * 4;
    int*   row_start = (int*)ws;                            ws += N_NODES * 4;
    int*   bsum      = (int*)ws;                            ws += SCAN_B * 4;
    uint2* csr_ew    = (uint2*)ws;                          ws += (size_t)N_EDGES * 8;
    __half* hWh      = (__half*)ws;                         // N*D halves

    // CSR build (once per call)
    k_zero <<<(N_NODES + 255) / 256, 256, 0, stream>>>(cnt);
    k_count<<<(N_EDGES + 255) / 256, 256, 0, stream>>>(dst, cnt);
    k_scan1<<<NBLK1, SCAN_B, 0, stream>>>(cnt, row_start, bsum);
    k_scan2<<<1, SCAN_B, 0, stream>>>(bsum);
    k_scan3<<<(N_NODES + 255) / 256, 256, 0, stream>>>(row_start, bsum, cnt, cursor, dinv);
    k_fill <<<(N_EDGES + 255) / 256, 256, 0, stream>>>(src, dst, cursor, dinv, csr_ew);

    const float* hin = x;
    int hstride = D;
    for (int l = 0; l < 3; ++l) {
        k_gemm64<<<(N_NODES + 63) / 64, 256, 0, stream>>>(hin, hstride, W[l], hWh);
        long long gthreads = (long long)N_NODES * 32;
        k_gather_elu<<<(int)((gthreads + 255) / 256), 256, 0, stream>>>(
            (const unsigned*)hWh, row_start, cnt, csr_ew, dinv, b[l], out, l * D);
        hin = out + l * D;      // read this layer's elu output back, strided
        hstride = 3 * D;
    }
}

// Round 5
// 297.820 us; speedup vs baseline: 2.5571x; 1.0851x over previous
//
#include <hip/hip_runtime.h>
#include <hip/hip_fp16.h>
#include <math.h>

#define N_NODES 50000
#define N_EDGES 800000
#define D 64
#define SCAN_B 256
#define NBLK1 ((N_NODES + SCAN_B - 1) / SCAN_B)   // 196
#define GEMM_BLOCKS ((N_NODES + 63) / 64)         // 782
#define FILL_BLOCKS ((N_EDGES + 255) / 256)       // 3125

// ---------------------------------------------------------------------------
// CSR build helpers
// ---------------------------------------------------------------------------
__global__ void k_zero(int* __restrict__ cnt) {
    int i = blockIdx.x * blockDim.x + threadIdx.x;
    if (i < N_NODES) cnt[i] = 0;
}

__global__ void k_count(const int* __restrict__ dst, int* __restrict__ cnt) {
    int e = blockIdx.x * blockDim.x + threadIdx.x;
    if (e < N_EDGES) atomicAdd(&cnt[dst[e]], 1);
}

// per-block exclusive scan of cnt -> row_start (partial), block totals -> bsum
__global__ void k_scan1(const int* __restrict__ cnt, int* __restrict__ row_start,
                        int* __restrict__ bsum) {
    __shared__ int s[SCAN_B];
    int t = threadIdx.x;
    int i = blockIdx.x * SCAN_B + t;
    int v = (i < N_NODES) ? cnt[i] : 0;
    s[t] = v;
    __syncthreads();
    #pragma unroll
    for (int off = 1; off < SCAN_B; off <<= 1) {
        int u = (t >= off) ? s[t - off] : 0;
        __syncthreads();
        s[t] += u;
        __syncthreads();
    }
    if (i < N_NODES) row_start[i] = s[t] - v;      // exclusive within block
    if (t == SCAN_B - 1) bsum[blockIdx.x] = s[t];  // block total
}

__global__ void k_scan2(int* __restrict__ bsum) {
    __shared__ int s[SCAN_B];
    int t = threadIdx.x;
    int v = (t < NBLK1) ? bsum[t] : 0;
    s[t] = v;
    __syncthreads();
    #pragma unroll
    for (int off = 1; off < SCAN_B; off <<= 1) {
        int u = (t >= off) ? s[t - off] : 0;
        __syncthreads();
        s[t] += u;
        __syncthreads();
    }
    if (t < NBLK1) bsum[t] = s[t] - v;             // exclusive
}

// add block offsets; cursor = row_start; dinv = rsqrt(cnt + 1)
__global__ void k_scan3(int* __restrict__ row_start, const int* __restrict__ bsum,
                        const int* __restrict__ cnt, int* __restrict__ cursor,
                        float* __restrict__ dinv) {
    int i = blockIdx.x * blockDim.x + threadIdx.x;
    if (i < N_NODES) {
        int rs = row_start[i] + bsum[i / SCAN_B];
        row_start[i] = rs;
        cursor[i] = rs;
        dinv[i] = rsqrtf((float)cnt[i] + 1.0f);
    }
}

// ---------------------------------------------------------------------------
// GEMM body: hWs[row,:] = (h[row,:] @ W) * dinv[row], fp16 out.
// 256 threads / 64 rows per block. W column in 64 VGPRs; h tile in LDS read
// as broadcast float4.
// ---------------------------------------------------------------------------
__device__ __forceinline__ void gemm64_body(const float* __restrict__ h, int hstride,
                                            const float* __restrict__ W,
                                            const float* __restrict__ dinv,
                                            __half* __restrict__ hWh, int row0) {
    __shared__ float hs[64][64];   // 16 KB
    int tid = threadIdx.x;
    int col = tid & 63;

    float wreg[64];
    #pragma unroll
    for (int k = 0; k < 64; ++k) wreg[k] = W[k * 64 + col];   // coalesced per k

    for (int i = tid; i < 64 * 64; i += 256) {
        int r = i >> 6, c = i & 63;
        int gr = row0 + r;
        hs[r][c] = (gr < N_NODES) ? h[(size_t)gr * hstride + c] : 0.0f;
    }
    __syncthreads();

    int rsub = tid >> 6;   // 0..3
    #pragma unroll
    for (int p = 0; p < 16; ++p) {
        int r = p * 4 + rsub;
        float acc = 0.0f;
        const float4* hp = (const float4*)hs[r];
        #pragma unroll
        for (int kk = 0; kk < 16; ++kk) {
            float4 hv = hp[kk];    // same addr for all lanes -> b128 broadcast
            acc += hv.x * wreg[4 * kk] + hv.y * wreg[4 * kk + 1]
                 + hv.z * wreg[4 * kk + 2] + hv.w * wreg[4 * kk + 3];
        }
        int gr = row0 + r;
        if (gr < N_NODES)
            hWh[((size_t)gr << 6) + col] = __float2half_rn(acc * dinv[gr]);
    }
}

__global__ __launch_bounds__(256) void k_gemm64(const float* __restrict__ h, int hstride,
                                                const float* __restrict__ W,
                                                const float* __restrict__ dinv,
                                                __half* __restrict__ hWh) {
    gemm64_body(h, hstride, W, dinv, hWh, blockIdx.x * 64);
}

// ---------------------------------------------------------------------------
// Merged: blocks [0, GEMM_BLOCKS) do layer-1 GEMM; the rest fill the CSR.
// Both depend only on scan3 output; fill's latency hides under GEMM compute.
// ---------------------------------------------------------------------------
__global__ __launch_bounds__(256) void k_gemm1_fill(
        const float* __restrict__ x, const float* __restrict__ W1,
        const float* __restrict__ dinv, __half* __restrict__ hWh,
        const int* __restrict__ src, const int* __restrict__ dst,
        int* __restrict__ cursor, int* __restrict__ csr_src) {
    if (blockIdx.x < GEMM_BLOCKS) {
        gemm64_body(x, D, W1, dinv, hWh, blockIdx.x * 64);
    } else {
        int e = (blockIdx.x - GEMM_BLOCKS) * 256 + threadIdx.x;
        if (e < N_EDGES) {
            int s = src[e], d = dst[e];
            int pos = atomicAdd(&cursor[d], 1);
            csr_src[pos] = s;
        }
    }
}

// ---------------------------------------------------------------------------
// Fused aggregate: half-wave (32 lanes) per node, lane owns a feature PAIR.
// acc = hWs[node] + sum_e hWs[src] ; out = b + dinv[node]*acc ; elu ; store.
// ---------------------------------------------------------------------------
__global__ __launch_bounds__(256) void k_gather_elu(
        const unsigned* __restrict__ hW2,      // [N][32] half2-packed (pre-scaled)
        const int* __restrict__ row_start,
        const int* __restrict__ cnt,
        const int* __restrict__ csr_src,
        const float* __restrict__ dinv,
        const float* __restrict__ bias,
        float* __restrict__ out, int col_off) {
    int gid = blockIdx.x * blockDim.x + threadIdx.x;
    int node = gid >> 5;
    if (node >= N_NODES) return;
    int fp = gid & 31;
    unsigned sv = hW2[((size_t)node << 5) + fp];
    float2 sf = __half22float2(*(const __half2*)&sv);
    float acc0 = sf.x, acc1 = sf.y;            // self message (pre-scaled by dinv[node])
    int beg = row_start[node];
    int n = cnt[node];
    int j = 0;
    for (; j + 4 <= n; j += 4) {
        int s0 = csr_src[beg + j];
        int s1 = csr_src[beg + j + 1];
        int s2 = csr_src[beg + j + 2];
        int s3 = csr_src[beg + j + 3];
        unsigned v0 = hW2[((size_t)s0 << 5) + fp];
        unsigned v1 = hW2[((size_t)s1 << 5) + fp];
        unsigned v2 = hW2[((size_t)s2 << 5) + fp];
        unsigned v3 = hW2[((size_t)s3 << 5) + fp];
        float2 f0 = __half22float2(*(const __half2*)&v0);
        float2 f1 = __half22float2(*(const __half2*)&v1);
        float2 f2 = __half22float2(*(const __half2*)&v2);
        float2 f3 = __half22float2(*(const __half2*)&v3);
        acc0 += (f0.x + f1.x) + (f2.x + f3.x);
        acc1 += (f0.y + f1.y) + (f2.y + f3.y);
    }
    for (; j < n; ++j) {
        int s0 = csr_src[beg + j];
        unsigned v0 = hW2[((size_t)s0 << 5) + fp];
        float2 f0 = __half22float2(*(const __half2*)&v0);
        acc0 += f0.x;
        acc1 += f0.y;
    }
    float dn = dinv[node];
    float2 bb = *(const float2*)&bias[2 * fp];
    acc0 = bb.x + dn * acc0;
    acc1 = bb.y + dn * acc1;
    acc0 = (acc0 > 0.0f) ? acc0 : expm1f(acc0);
    acc1 = (acc1 > 0.0f) ? acc1 : expm1f(acc1);
    *(float2*)&out[(size_t)node * (3 * D) + col_off + 2 * fp] = make_float2(acc0, acc1);
}

extern "C" void kernel_launch(void* const* d_in, const int* in_sizes, int n_in,
                              void* d_out, int out_size, void* d_ws, size_t ws_size,
                              hipStream_t stream) {
    const float* x   = (const float*)d_in[0];
    const int*   ei  = (const int*)d_in[1];
    const int*   src = ei;
    const int*   dst = ei + N_EDGES;
    const float* W[3] = {(const float*)d_in[2], (const float*)d_in[4], (const float*)d_in[6]};
    const float* b[3] = {(const float*)d_in[3], (const float*)d_in[5], (const float*)d_in[7]};
    float* out = (float*)d_out;

    // workspace layout
    char* ws = (char*)d_ws;
    float* dinv      = (float*)ws;                          ws += N_NODES * 4;
    int*   cnt       = (int*)ws;                            ws += N_NODES * 4;
    int*   cursor    = (int*)ws;                            ws += N_NODES * 4;
    int*   row_start = (int*)ws;                            ws += N_NODES * 4;
    int*   bsum      = (int*)ws;                            ws += SCAN_B * 4;
    int*   csr_src   = (int*)ws;                            ws += (size_t)N_EDGES * 4;
    __half* hWh      = (__half*)ws;                         // N*D halves

    // degree + scan (CSR skeleton)
    k_zero <<<(N_NODES + 255) / 256, 256, 0, stream>>>(cnt);
    k_count<<<(N_EDGES + 255) / 256, 256, 0, stream>>>(dst, cnt);
    k_scan1<<<NBLK1, SCAN_B, 0, stream>>>(cnt, row_start, bsum);
    k_scan2<<<1, SCAN_B, 0, stream>>>(bsum);
    k_scan3<<<(N_NODES + 255) / 256, 256, 0, stream>>>(row_start, bsum, cnt, cursor, dinv);

    // layer 1 GEMM (pre-scaled by dinv) overlapped with CSR fill
    k_gemm1_fill<<<GEMM_BLOCKS + FILL_BLOCKS, 256, 0, stream>>>(
        x, W[0], dinv, hWh, src, dst, cursor, csr_src);

    long long gthreads = (long long)N_NODES * 32;
    int gather_grid = (int)((gthreads + 255) / 256);

    // layer 1 aggregate
    k_gather_elu<<<gather_grid, 256, 0, stream>>>(
        (const unsigned*)hWh, row_start, cnt, csr_src, dinv, b[0], out, 0);

    // layers 2, 3
    for (int l = 1; l < 3; ++l) {
        k_gemm64<<<GEMM_BLOCKS, 256, 0, stream>>>(out + (l - 1) * D, 3 * D, W[l], dinv, hWh);
        k_gather_elu<<<gather_grid, 256, 0, stream>>>(
            (const unsigned*)hWh, row_start, cnt, csr_src, dinv, b[l], out, l * D);
    }
}